// Round 1
// baseline (458.575 us; speedup 1.0000x reference)
//
#include <hip/hip_runtime.h>

#define NTOK 8192
#define NCH  256
#define TS   32      // tokens per tile
#define XP   40      // row stride (bf16 elems) for [ch][tok] tiles (16B-aligned rows)
#define VP   264     // row stride (bf16 elems) for vt transposed [tok][ch]
#define CTX_PART (8*32*33)   // per-block partial: 8 heads x 32 k x (32 v + 1 denom)
#define KGRP 128     // token-groups for k_ctx (each block does 2 tiles)

typedef unsigned short u16;

__device__ __forceinline__ float b2f(u16 h){
  union{unsigned u; float f;} x; x.u = ((unsigned)h) << 16; return x.f;
}
__device__ __forceinline__ u16 f2b(float f){
  union{float f; unsigned u;} x; x.f = f;
  unsigned u = x.u;
  unsigned r = (u + 0x7FFFu + ((u >> 16) & 1u)) >> 16;   // RNE
  return (u16)r;
}

// ---------------------------------------------------------------------------
// Kernel 1: per token-tile compute K = Wk@x+bk (then exp) and V = Wv@x+bv,
// accumulate per-block partial ctx numerators (ek_h @ V_h^T) and denominators
// (row-sums of ek, fused as a 33rd column). Partials -> ws (no atomics).
// ---------------------------------------------------------------------------
__global__ __launch_bounds__(256)
void k_ctx(const float* __restrict__ x,
           const float* __restrict__ Wk, const float* __restrict__ bk,
           const float* __restrict__ Wv, const float* __restrict__ bv,
           float* __restrict__ partials)
{
  __shared__ u16 xs[NCH * XP];   // x tile  [ch][tok] bf16
  __shared__ u16 ek[NCH * XP];   // exp(K)  [ch][tok] bf16
  __shared__ u16 vt[TS * VP];    // V tile transposed [tok][ch] bf16

  const int t  = threadIdx.x;
  const int b  = blockIdx.x >> 7;      // 4 batches x 128 groups
  const int g  = blockIdx.x & 127;
  const int tx = t & 7;                // token quad: s = tx*4 + j
  const int ty = t >> 3;               // channel group: o = ty*8 + r
  const int h  = t >> 5;               // head (ctx phase)
  const int kk = t & 31;               // key channel within head (ctx phase)

  float acc2[33];
  #pragma unroll
  for (int i = 0; i < 33; ++i) acc2[i] = 0.f;

  const float* xb = x + (size_t)b * NCH * NTOK;

  for (int c = 0; c < 2; ++c) {
    const int s0 = (g * 2 + c) * TS;

    // ---- stage x tile (fp32 global -> bf16 LDS), coalesced float4 loads ----
    #pragma unroll
    for (int r = 0; r < 8; ++r) {
      int f = r * 256 + t;
      int row = f >> 3, col = (f & 7) * 4;
      float4 v = *(const float4*)(xb + (size_t)row * NTOK + s0 + col);
      u16* p = &xs[row * XP + col];
      p[0] = f2b(v.x); p[1] = f2b(v.y); p[2] = f2b(v.z); p[3] = f2b(v.w);
    }
    __syncthreads();

    // ---- K GEMM: acc[r][j] = bk[o] + sum_k Wk[o][k] * xs[k][s] ----
    {
      float acc[8][4];
      #pragma unroll
      for (int r = 0; r < 8; ++r) {
        float bb = bk[ty * 8 + r];
        acc[r][0] = bb; acc[r][1] = bb; acc[r][2] = bb; acc[r][3] = bb;
      }
      for (int k = 0; k < NCH; k += 4) {
        float xq[4][4];
        #pragma unroll
        for (int i = 0; i < 4; ++i) {
          ushort4 q = *(const ushort4*)&xs[(k + i) * XP + tx * 4];
          xq[i][0] = b2f(q.x); xq[i][1] = b2f(q.y);
          xq[i][2] = b2f(q.z); xq[i][3] = b2f(q.w);
        }
        #pragma unroll
        for (int r = 0; r < 8; ++r) {
          float4 w = *(const float4*)(Wk + (size_t)(ty * 8 + r) * NCH + k);
          #pragma unroll
          for (int j = 0; j < 4; ++j)
            acc[r][j] += w.x * xq[0][j] + w.y * xq[1][j] + w.z * xq[2][j] + w.w * xq[3][j];
        }
      }
      // exp + store ek (packed 8B stores)
      #pragma unroll
      for (int r = 0; r < 8; ++r) {
        ushort4 q;
        q.x = f2b(__expf(acc[r][0])); q.y = f2b(__expf(acc[r][1]));
        q.z = f2b(__expf(acc[r][2])); q.w = f2b(__expf(acc[r][3]));
        *(ushort4*)&ek[(ty * 8 + r) * XP + tx * 4] = q;
      }
    }

    // ---- V GEMM -> vt (transposed [tok][ch]) ----
    {
      float acc[8][4];
      #pragma unroll
      for (int r = 0; r < 8; ++r) {
        float bb = bv[ty * 8 + r];
        acc[r][0] = bb; acc[r][1] = bb; acc[r][2] = bb; acc[r][3] = bb;
      }
      for (int k = 0; k < NCH; k += 4) {
        float xq[4][4];
        #pragma unroll
        for (int i = 0; i < 4; ++i) {
          ushort4 q = *(const ushort4*)&xs[(k + i) * XP + tx * 4];
          xq[i][0] = b2f(q.x); xq[i][1] = b2f(q.y);
          xq[i][2] = b2f(q.z); xq[i][3] = b2f(q.w);
        }
        #pragma unroll
        for (int r = 0; r < 8; ++r) {
          float4 w = *(const float4*)(Wv + (size_t)(ty * 8 + r) * NCH + k);
          #pragma unroll
          for (int j = 0; j < 4; ++j)
            acc[r][j] += w.x * xq[0][j] + w.y * xq[1][j] + w.z * xq[2][j] + w.w * xq[3][j];
        }
      }
      #pragma unroll
      for (int r = 0; r < 8; ++r)
        #pragma unroll
        for (int j = 0; j < 4; ++j)
          vt[(tx * 4 + j) * VP + ty * 8 + r] = f2b(acc[r][j]);
    }
    __syncthreads();

    // ---- ctx accumulate: thread (h, kk): acc2[v] += ek[h*32+kk][s]*V[h*32+v][s]
    //      acc2[32] += ek (denominator) ----
    {
      float er[TS];
      const u16* p = &ek[(h * 32 + kk) * XP];
      #pragma unroll
      for (int s = 0; s < TS; s += 4) {
        ushort4 q = *(const ushort4*)(p + s);
        er[s] = b2f(q.x); er[s+1] = b2f(q.y); er[s+2] = b2f(q.z); er[s+3] = b2f(q.w);
      }
      for (int s = 0; s < TS; ++s) {
        float e = er[s];
        acc2[32] += e;
        const u16* vp = &vt[s * VP + h * 32];
        #pragma unroll
        for (int v = 0; v < 32; v += 4) {
          ushort4 q = *(const ushort4*)(vp + v);
          acc2[v]     += e * b2f(q.x);
          acc2[v + 1] += e * b2f(q.y);
          acc2[v + 2] += e * b2f(q.z);
          acc2[v + 3] += e * b2f(q.w);
        }
      }
    }
    // no barrier needed here: next iter's stage only writes xs (not read by
    // ctx phase), and the post-stage barrier orders ek/vt rewrites.
  }

  float* dst = partials + (size_t)(b * KGRP + g) * CTX_PART + (h * 32 + kk) * 33;
  #pragma unroll
  for (int i = 0; i < 33; ++i) dst[i] = acc2[i];
}

// ---------------------------------------------------------------------------
// Kernel 2: reduce per-block partials -> ctxF[4][8][32][32], denomF[4][256]
// ---------------------------------------------------------------------------
__global__ __launch_bounds__(256)
void k_red(const float* __restrict__ partials,
           float* __restrict__ ctxF, float* __restrict__ denomF)
{
  int i = blockIdx.x * 256 + threadIdx.x;
  if (i < 4 * 8192) {
    int b = i >> 13, rem = i & 8191;
    int ch = rem >> 5, v = rem & 31;
    const float* p = partials + (size_t)b * KGRP * CTX_PART + ch * 33 + v;
    float s = 0.f;
    for (int g = 0; g < KGRP; ++g) s += p[(size_t)g * CTX_PART];
    ctxF[i] = s;
  } else if (i < 4 * 8192 + 4 * 256) {
    int j = i - 4 * 8192;
    int b = j >> 8, ch = j & 255;
    const float* p = partials + (size_t)b * KGRP * CTX_PART + ch * 33 + 32;
    float s = 0.f;
    for (int g = 0; g < KGRP; ++g) s += p[(size_t)g * CTX_PART];
    denomF[j] = s;
  }
}

// ---------------------------------------------------------------------------
// Kernel 3: Q GEMM -> exp -> per-head softmax folded with 1/denom ->
// att = ctxN^T @ qn (per head) -> rep = Wr@att + br -> + residual -> store
// transposed to (b, s, o).
// ---------------------------------------------------------------------------
__global__ __launch_bounds__(256)
void k_out(const float* __restrict__ x,
           const float* __restrict__ Wq, const float* __restrict__ bq,
           const float* __restrict__ Wr, const float* __restrict__ br,
           const float* __restrict__ ctxF, const float* __restrict__ denomF,
           float* __restrict__ out)
{
  __shared__ u16 xs[NCH * XP];   // x tile [ch][tok]
  __shared__ u16 eq[NCH * XP];   // exp(Q) -> normalized qn, in place
  __shared__ u16 at[NCH * XP];   // attended [ch][tok]

  const int t  = threadIdx.x;
  const int b  = blockIdx.x >> 8;     // 4 batches x 256 tiles
  const int g  = blockIdx.x & 255;
  const int s0 = g * TS;
  const int tx = t & 7, ty = t >> 3;
  const float* xb = x + (size_t)b * NCH * NTOK;

  // ---- stage x tile ----
  #pragma unroll
  for (int r = 0; r < 8; ++r) {
    int f = r * 256 + t;
    int row = f >> 3, col = (f & 7) * 4;
    float4 v = *(const float4*)(xb + (size_t)row * NTOK + s0 + col);
    u16* p = &xs[row * XP + col];
    p[0] = f2b(v.x); p[1] = f2b(v.y); p[2] = f2b(v.z); p[3] = f2b(v.w);
  }
  __syncthreads();

  // ---- Q GEMM -> exp -> eq ----
  {
    float acc[8][4];
    #pragma unroll
    for (int r = 0; r < 8; ++r) {
      float bb = bq[ty * 8 + r];
      acc[r][0] = bb; acc[r][1] = bb; acc[r][2] = bb; acc[r][3] = bb;
    }
    for (int k = 0; k < NCH; k += 4) {
      float xq[4][4];
      #pragma unroll
      for (int i = 0; i < 4; ++i) {
        ushort4 q = *(const ushort4*)&xs[(k + i) * XP + tx * 4];
        xq[i][0] = b2f(q.x); xq[i][1] = b2f(q.y);
        xq[i][2] = b2f(q.z); xq[i][3] = b2f(q.w);
      }
      #pragma unroll
      for (int r = 0; r < 8; ++r) {
        float4 w = *(const float4*)(Wq + (size_t)(ty * 8 + r) * NCH + k);
        #pragma unroll
        for (int j = 0; j < 4; ++j)
          acc[r][j] += w.x * xq[0][j] + w.y * xq[1][j] + w.z * xq[2][j] + w.w * xq[3][j];
      }
    }
    #pragma unroll
    for (int r = 0; r < 8; ++r) {
      ushort4 q;
      q.x = f2b(__expf(acc[r][0])); q.y = f2b(__expf(acc[r][1]));
      q.z = f2b(__expf(acc[r][2])); q.w = f2b(__expf(acc[r][3]));
      *(ushort4*)&eq[(ty * 8 + r) * XP + tx * 4] = q;
    }
  }
  __syncthreads();

  // ---- per-(head, token) softmax normalize, fold 1/denom: qn = eq/(sum*denom) ----
  {
    int h = t >> 5, s = t & 31;
    float vals[32]; float sum = 0.f;
    const u16* p = &eq[(h * 32) * XP + s];
    #pragma unroll
    for (int k = 0; k < 32; ++k) { vals[k] = b2f(p[k * XP]); sum += vals[k]; }
    float inv = 1.0f / sum;
    const float* dn = denomF + b * 256 + h * 32;
    #pragma unroll
    for (int k = 0; k < 32; ++k)
      eq[(h * 32 + k) * XP + s] = f2b(vals[k] * inv / dn[k]);
  }
  __syncthreads();

  // ---- att: thread (h, v): at[h*32+v][s] = sum_k ctxN[h,k,v] * qn[h*32+k][s] ----
  {
    int h = t >> 5, v = t & 31;
    float acc3[TS];
    #pragma unroll
    for (int s = 0; s < TS; ++s) acc3[s] = 0.f;
    const float* cp = ctxF + (size_t)((b * 8 + h) * 32) * 32 + v;
    for (int k = 0; k < 32; ++k) {
      float cv = cp[(size_t)k * 32];
      const u16* qp = &eq[(h * 32 + k) * XP];
      #pragma unroll
      for (int s = 0; s < TS; s += 4) {
        ushort4 q = *(const ushort4*)(qp + s);
        acc3[s]     += cv * b2f(q.x);
        acc3[s + 1] += cv * b2f(q.y);
        acc3[s + 2] += cv * b2f(q.z);
        acc3[s + 3] += cv * b2f(q.w);
      }
    }
    u16* ap = &at[(h * 32 + v) * XP];
    #pragma unroll
    for (int s = 0; s < TS; s += 4) {
      ushort4 q;
      q.x = f2b(acc3[s]); q.y = f2b(acc3[s+1]); q.z = f2b(acc3[s+2]); q.w = f2b(acc3[s+3]);
      *(ushort4*)(ap + s) = q;
    }
  }
  __syncthreads();

  // ---- rep GEMM + residual + transposed store ----
  {
    float acc[8][4];
    #pragma unroll
    for (int r = 0; r < 8; ++r) {
      float bb = br[ty * 8 + r];
      acc[r][0] = bb; acc[r][1] = bb; acc[r][2] = bb; acc[r][3] = bb;
    }
    for (int v = 0; v < NCH; v += 4) {
      float aq[4][4];
      #pragma unroll
      for (int i = 0; i < 4; ++i) {
        ushort4 q = *(const ushort4*)&at[(v + i) * XP + tx * 4];
        aq[i][0] = b2f(q.x); aq[i][1] = b2f(q.y);
        aq[i][2] = b2f(q.z); aq[i][3] = b2f(q.w);
      }
      #pragma unroll
      for (int r = 0; r < 8; ++r) {
        float4 w = *(const float4*)(Wr + (size_t)(ty * 8 + r) * NCH + v);
        #pragma unroll
        for (int j = 0; j < 4; ++j)
          acc[r][j] += w.x * aq[0][j] + w.y * aq[1][j] + w.z * aq[2][j] + w.w * aq[3][j];
      }
    }
    // residual (from bf16 xs tile) + store to out[b, s, o]
    float res[8][4];
    #pragma unroll
    for (int r = 0; r < 8; ++r) {
      ushort4 q = *(const ushort4*)&xs[(ty * 8 + r) * XP + tx * 4];
      res[r][0] = b2f(q.x); res[r][1] = b2f(q.y); res[r][2] = b2f(q.z); res[r][3] = b2f(q.w);
    }
    #pragma unroll
    for (int j = 0; j < 4; ++j) {
      int s = s0 + tx * 4 + j;
      float* op = out + (size_t)b * NTOK * NCH + (size_t)s * NCH + ty * 8;
      float4 o1, o2;
      o1.x = acc[0][j] + res[0][j]; o1.y = acc[1][j] + res[1][j];
      o1.z = acc[2][j] + res[2][j]; o1.w = acc[3][j] + res[3][j];
      o2.x = acc[4][j] + res[4][j]; o2.y = acc[5][j] + res[5][j];
      o2.z = acc[6][j] + res[6][j]; o2.w = acc[7][j] + res[7][j];
      *(float4*)op = o1;
      *(float4*)(op + 4) = o2;
    }
  }
}

extern "C" void kernel_launch(void* const* d_in, const int* in_sizes, int n_in,
                              void* d_out, int out_size, void* d_ws, size_t ws_size,
                              hipStream_t stream) {
  const float* x  = (const float*)d_in[0];
  const float* Wk = (const float*)d_in[1];
  const float* bk = (const float*)d_in[2];
  const float* Wq = (const float*)d_in[3];
  const float* bq = (const float*)d_in[4];
  const float* Wv = (const float*)d_in[5];
  const float* bv = (const float*)d_in[6];
  const float* Wr = (const float*)d_in[7];
  const float* br = (const float*)d_in[8];
  float* out = (float*)d_out;

  float* ws       = (float*)d_ws;
  float* partials = ws;                                  // 4*128*8448 floats
  float* ctxF     = ws + (size_t)4 * KGRP * CTX_PART;    // 32768 floats
  float* denomF   = ctxF + 32768;                        // 1024 floats

  hipLaunchKernelGGL(k_ctx, dim3(4 * KGRP), dim3(256), 0, stream,
                     x, Wk, bk, Wv, bv, partials);
  hipLaunchKernelGGL(k_red, dim3(132), dim3(256), 0, stream,
                     partials, ctxF, denomF);
  hipLaunchKernelGGL(k_out, dim3(4 * 256), dim3(256), 0, stream,
                     x, Wq, bq, Wr, br, ctxF, denomF, out);
}

// Round 2
// 158.794 us; speedup vs baseline: 2.8879x; 2.8879x over previous
//
#include <hip/hip_runtime.h>

#define NTOK 8192
#define NCH  256
#define TT   64          // tokens per tile
#define XTP  264         // stride (u16) for [tok][ch] LDS tiles (16B-aligned rows)
#define EKP  72          // stride (u16) for [ch][tok] LDS tiles (16B-aligned rows)

typedef unsigned short u16;
typedef __attribute__((ext_vector_type(8))) short bf16x8;   // MFMA A/B frag (4 VGPR)
typedef __attribute__((ext_vector_type(4))) float f32x4;    // MFMA C/D frag
typedef __attribute__((ext_vector_type(8))) unsigned short u16x8;
typedef __attribute__((ext_vector_type(4))) unsigned short u16x4;

__device__ __forceinline__ float b2f(u16 h){
  union{unsigned u; float f;} x; x.u = ((unsigned)h) << 16; return x.f;
}
__device__ __forceinline__ u16 f2b(float f){
  union{float f; unsigned u;} x; x.f = f;
  unsigned u = x.u;
  return (u16)((u + 0x7FFFu + ((u >> 16) & 1u)) >> 16);   // RNE
}
__device__ __forceinline__ f32x4 mfma16(bf16x8 a, bf16x8 b, f32x4 c){
  return __builtin_amdgcn_mfma_f32_16x16x32_bf16(a, b, c, 0, 0, 0);
}

// ---------------------------------------------------------------------------
// k_prep: (a) transpose+convert x fp32 [b][ch][tok] -> xT bf16 [b][tok][ch]
//         (b) convert Wk/Wq/Wv/Wr fp32 -> bf16 row-major into wbf
// ---------------------------------------------------------------------------
__global__ __launch_bounds__(256)
void k_prep(const float* __restrict__ x,
            const float* __restrict__ Wk, const float* __restrict__ Wq,
            const float* __restrict__ Wv, const float* __restrict__ Wr,
            u16* __restrict__ xT, u16* __restrict__ wbf)
{
  __shared__ u16 ts[64 * 68];
  const int t = threadIdx.x, bid = blockIdx.x;
  if (bid < 2048) {
    const int b = bid >> 9, rem = bid & 511, tg = rem >> 2, cg = rem & 3;
    const float* xb = x + (size_t)b * NCH * NTOK;
    #pragma unroll
    for (int p = 0; p < 4; ++p) {
      int cl = p * 16 + (t >> 4);
      int tl = (t & 15) * 4;
      float4 v = *(const float4*)(xb + (size_t)(cg * 64 + cl) * NTOK + tg * 64 + tl);
      u16x4 pk; pk[0]=f2b(v.x); pk[1]=f2b(v.y); pk[2]=f2b(v.z); pk[3]=f2b(v.w);
      *(u16x4*)&ts[cl * 68 + tl] = pk;
    }
    __syncthreads();
    #pragma unroll
    for (int p = 0; p < 2; ++p) {
      int tl = p * 32 + (t >> 3);
      int cl = (t & 7) * 8;
      u16x8 o;
      #pragma unroll
      for (int j = 0; j < 8; ++j) o[j] = ts[(cl + j) * 68 + tl];
      *(u16x8*)(xT + (((size_t)(b * NTOK + tg * 64 + tl)) << 8) + cg * 64 + cl) = o;
    }
  } else {
    const int wb = bid - 2048;           // 64 blocks, 16 per matrix
    const int mat = wb >> 4;
    const float* src = (mat == 0) ? Wk : (mat == 1) ? Wq : (mat == 2) ? Wv : Wr;
    u16* dst = wbf + mat * 65536;
    const int base = (wb & 15) * 4096 + t * 16;
    #pragma unroll
    for (int i = 0; i < 4; ++i) {
      float4 v = *(const float4*)(src + base + i * 4);
      u16x4 pk; pk[0]=f2b(v.x); pk[1]=f2b(v.y); pk[2]=f2b(v.z); pk[3]=f2b(v.w);
      *(u16x4*)(dst + base + i * 4) = pk;
    }
  }
}

// ---------------------------------------------------------------------------
// k_ctx: per 64-token tile: K-GEMM(MFMA)->exp->ek LDS; V-GEMM->vt LDS (aliased
// over x tile); ctx GEMM (token reduction, MFMA) + denom row-sums -> partials.
// ---------------------------------------------------------------------------
__global__ __launch_bounds__(256)
void k_ctx(const u16* __restrict__ xT, const u16* __restrict__ wbf,
           const float* __restrict__ bk, const float* __restrict__ bv,
           u16* __restrict__ ctxPart, float* __restrict__ denomPart)
{
  __shared__ u16 bufA[NCH * EKP];   // phase 1: xT tile [64][XTP]; phase 2: vt [256][EKP]
  __shared__ u16 ekb[NCH * EKP];    // exp(K) [ch][tok]

  const int t = threadIdx.x;
  const int b = blockIdx.x >> 7, g = blockIdx.x & 127;
  const int w = t >> 6, lane = t & 63;
  const int l15 = lane & 15, quad = lane >> 4;
  const u16* Wkb = wbf;
  const u16* Wvb = wbf + 2 * 65536;

  // ---- stage xT tile (32 KB contiguous, coalesced 16B) ----
  {
    const u16* src = xT + ((size_t)(b * NTOK + g * TT) << 8);
    #pragma unroll
    for (int i = 0; i < 8; ++i) {
      int f = i * 2048 + t * 8;
      int tok = f >> 8, ch = f & 255;
      *(u16x8*)&bufA[tok * XTP + ch] = *(const u16x8*)(src + f);
    }
  }
  __syncthreads();

  f32x4 acc[4][4];

  // ---- K GEMM: D[och][tok], wave w owns och [64w,64w+64) ----
  #pragma unroll
  for (int mi = 0; mi < 4; ++mi)
    #pragma unroll
    for (int nj = 0; nj < 4; ++nj) acc[mi][nj] = (f32x4)0.f;
  for (int k0 = 0; k0 < NCH; k0 += 32) {
    bf16x8 af[4], bx[4];
    #pragma unroll
    for (int mi = 0; mi < 4; ++mi)
      af[mi] = *(const bf16x8*)(Wkb + (size_t)(w * 64 + mi * 16 + l15) * NCH + k0 + quad * 8);
    #pragma unroll
    for (int nj = 0; nj < 4; ++nj)
      bx[nj] = *(const bf16x8*)&bufA[(nj * 16 + l15) * XTP + k0 + quad * 8];
    #pragma unroll
    for (int mi = 0; mi < 4; ++mi)
      #pragma unroll
      for (int nj = 0; nj < 4; ++nj) acc[mi][nj] = mfma16(af[mi], bx[nj], acc[mi][nj]);
  }
  // epilogue: bias + exp -> ekb [ch][tok]
  #pragma unroll
  for (int mi = 0; mi < 4; ++mi) {
    float4 bb = *(const float4*)(bk + w * 64 + mi * 16 + quad * 4);
    #pragma unroll
    for (int nj = 0; nj < 4; ++nj) {
      int tok = nj * 16 + l15, chb = w * 64 + mi * 16 + quad * 4;
      ekb[(chb + 0) * EKP + tok] = f2b(__expf(acc[mi][nj][0] + bb.x));
      ekb[(chb + 1) * EKP + tok] = f2b(__expf(acc[mi][nj][1] + bb.y));
      ekb[(chb + 2) * EKP + tok] = f2b(__expf(acc[mi][nj][2] + bb.z));
      ekb[(chb + 3) * EKP + tok] = f2b(__expf(acc[mi][nj][3] + bb.w));
    }
  }

  // ---- V GEMM (re-uses acc regs) ----
  #pragma unroll
  for (int mi = 0; mi < 4; ++mi)
    #pragma unroll
    for (int nj = 0; nj < 4; ++nj) acc[mi][nj] = (f32x4)0.f;
  for (int k0 = 0; k0 < NCH; k0 += 32) {
    bf16x8 af[4], bx[4];
    #pragma unroll
    for (int mi = 0; mi < 4; ++mi)
      af[mi] = *(const bf16x8*)(Wvb + (size_t)(w * 64 + mi * 16 + l15) * NCH + k0 + quad * 8);
    #pragma unroll
    for (int nj = 0; nj < 4; ++nj)
      bx[nj] = *(const bf16x8*)&bufA[(nj * 16 + l15) * XTP + k0 + quad * 8];
    #pragma unroll
    for (int mi = 0; mi < 4; ++mi)
      #pragma unroll
      for (int nj = 0; nj < 4; ++nj) acc[mi][nj] = mfma16(af[mi], bx[nj], acc[mi][nj]);
  }
  __syncthreads();   // all waves done reading x tile; safe to overwrite with vt
  #pragma unroll
  for (int mi = 0; mi < 4; ++mi) {
    float4 bb = *(const float4*)(bv + w * 64 + mi * 16 + quad * 4);
    #pragma unroll
    for (int nj = 0; nj < 4; ++nj) {
      int tok = nj * 16 + l15, chb = w * 64 + mi * 16 + quad * 4;
      bufA[(chb + 0) * EKP + tok] = f2b(acc[mi][nj][0] + bb.x);
      bufA[(chb + 1) * EKP + tok] = f2b(acc[mi][nj][1] + bb.y);
      bufA[(chb + 2) * EKP + tok] = f2b(acc[mi][nj][2] + bb.z);
      bufA[(chb + 3) * EKP + tok] = f2b(acc[mi][nj][3] + bb.w);
    }
  }
  __syncthreads();

  // ---- ctx GEMM: wave w -> heads 2w, 2w+1. D[kk][vch] = sum_s ek*v ----
  f32x4 cacc[2][2][2];
  #pragma unroll
  for (int hl = 0; hl < 2; ++hl)
    #pragma unroll
    for (int mi = 0; mi < 2; ++mi)
      #pragma unroll
      for (int nj = 0; nj < 2; ++nj) cacc[hl][mi][nj] = (f32x4)0.f;
  #pragma unroll
  for (int hl = 0; hl < 2; ++hl) {
    int hh = 2 * w + hl;
    #pragma unroll
    for (int kc = 0; kc < 2; ++kc) {
      bf16x8 ae[2], bvv[2];
      #pragma unroll
      for (int mi = 0; mi < 2; ++mi)
        ae[mi] = *(const bf16x8*)&ekb[(hh * 32 + mi * 16 + l15) * EKP + kc * 32 + quad * 8];
      #pragma unroll
      for (int nj = 0; nj < 2; ++nj)
        bvv[nj] = *(const bf16x8*)&bufA[(hh * 32 + nj * 16 + l15) * EKP + kc * 32 + quad * 8];
      #pragma unroll
      for (int mi = 0; mi < 2; ++mi)
        #pragma unroll
        for (int nj = 0; nj < 2; ++nj)
          cacc[hl][mi][nj] = mfma16(ae[mi], bvv[nj], cacc[hl][mi][nj]);
    }
  }
  // denominator: thread t sums ek row t over 64 tokens
  float dsum = 0.f;
  #pragma unroll
  for (int s = 0; s < TT; s += 8) {
    u16x8 v = *(const u16x8*)&ekb[t * EKP + s];
    #pragma unroll
    for (int j = 0; j < 8; ++j) dsum += b2f(v[j]);
  }

  // ---- store partials (bf16 ctx + fp32 denom) ----
  u16* cp = ctxPart + ((size_t)(b * 128 + g) << 13);
  #pragma unroll
  for (int hl = 0; hl < 2; ++hl)
    #pragma unroll
    for (int mi = 0; mi < 2; ++mi)
      #pragma unroll
      for (int nj = 0; nj < 2; ++nj)
        #pragma unroll
        for (int r = 0; r < 4; ++r) {
          int e = (((2 * w + hl) * 32 + mi * 16 + quad * 4 + r) << 5) + nj * 16 + l15;
          cp[e] = f2b(cacc[hl][mi][nj][r]);
        }
  denomPart[(size_t)(b * 128 + g) * 256 + t] = dsum;
}

// ---------------------------------------------------------------------------
// k_red: sum 128 partials -> ctxT bf16 [b][h][vch][kk] (A-operand-ready) and
// rdenomF = 1/denom fp32 [b][256]
// ---------------------------------------------------------------------------
__global__ __launch_bounds__(256)
void k_red(const u16* __restrict__ ctxPart, const float* __restrict__ denomPart,
           u16* __restrict__ ctxT, float* __restrict__ rdenomF)
{
  int i = blockIdx.x * 256 + threadIdx.x;
  if (i < 32768) {
    int b = i >> 13, e = i & 8191;
    const u16* p = ctxPart + ((size_t)(b * 128) << 13) + e;
    float s = 0.f;
    for (int g = 0; g < 128; ++g) s += b2f(p[(size_t)g << 13]);
    int hh = e >> 10, kk = (e >> 5) & 31, vch = e & 31;
    ctxT[(((b * 8 + hh) * 32 + vch) << 5) + kk] = f2b(s);
  } else if (i < 33792) {
    int j = i - 32768, b = j >> 8, ch = j & 255;
    const float* p = denomPart + (size_t)(b * 128) * 256 + ch;
    float s = 0.f;
    for (int g = 0; g < 128; ++g) s += p[(size_t)g << 8];
    rdenomF[j] = 1.0f / s;
  }
}

// ---------------------------------------------------------------------------
// k_out: Q-GEMM(MFMA)->exp->head softmax (shfl over quads) * rdenom -> qn LDS
// [tok][ch]; att GEMM (A=ctxT global, B=qn, out aliased over qn); Wr-GEMM;
// +bias +bf16 residual; coalesced float4 transposed store.
// ---------------------------------------------------------------------------
__global__ __launch_bounds__(256)
void k_out(const u16* __restrict__ xT, const u16* __restrict__ wbf,
           const float* __restrict__ bq, const float* __restrict__ br,
           const u16* __restrict__ ctxT, const float* __restrict__ rdenomF,
           float* __restrict__ out)
{
  __shared__ u16 xs[TT * XTP];
  __shared__ u16 qs[TT * XTP];   // qn, then aliased by att (wave-exclusive cols)

  const int t = threadIdx.x;
  const int b = blockIdx.x >> 7, g = blockIdx.x & 127;
  const int w = t >> 6, lane = t & 63;
  const int l15 = lane & 15, quad = lane >> 4;
  const u16* Wqb = wbf + 65536;
  const u16* Wrb = wbf + 3 * 65536;

  {
    const u16* src = xT + ((size_t)(b * NTOK + g * TT) << 8);
    #pragma unroll
    for (int i = 0; i < 8; ++i) {
      int f = i * 2048 + t * 8;
      int tok = f >> 8, ch = f & 255;
      *(u16x8*)&xs[tok * XTP + ch] = *(const u16x8*)(src + f);
    }
  }
  __syncthreads();

  f32x4 acc[4][4];
  // ---- Q GEMM ----
  #pragma unroll
  for (int mi = 0; mi < 4; ++mi)
    #pragma unroll
    for (int nj = 0; nj < 4; ++nj) acc[mi][nj] = (f32x4)0.f;
  for (int k0 = 0; k0 < NCH; k0 += 32) {
    bf16x8 af[4], bx[4];
    #pragma unroll
    for (int mi = 0; mi < 4; ++mi)
      af[mi] = *(const bf16x8*)(Wqb + (size_t)(w * 64 + mi * 16 + l15) * NCH + k0 + quad * 8);
    #pragma unroll
    for (int nj = 0; nj < 4; ++nj)
      bx[nj] = *(const bf16x8*)&xs[(nj * 16 + l15) * XTP + k0 + quad * 8];
    #pragma unroll
    for (int mi = 0; mi < 4; ++mi)
      #pragma unroll
      for (int nj = 0; nj < 4; ++nj) acc[mi][nj] = mfma16(af[mi], bx[nj], acc[mi][nj]);
  }
  // bias + exp (in place)
  #pragma unroll
  for (int mi = 0; mi < 4; ++mi) {
    float4 bb = *(const float4*)(bq + w * 64 + mi * 16 + quad * 4);
    #pragma unroll
    for (int nj = 0; nj < 4; ++nj) {
      acc[mi][nj][0] = __expf(acc[mi][nj][0] + bb.x);
      acc[mi][nj][1] = __expf(acc[mi][nj][1] + bb.y);
      acc[mi][nj][2] = __expf(acc[mi][nj][2] + bb.z);
      acc[mi][nj][3] = __expf(acc[mi][nj][3] + bb.w);
    }
  }
  // per-(head, token) softmax denom: mi pair within wave + quad reduction
  float inv[2][4];
  #pragma unroll
  for (int hl = 0; hl < 2; ++hl)
    #pragma unroll
    for (int nj = 0; nj < 4; ++nj) {
      float s = 0.f;
      #pragma unroll
      for (int mi = 2 * hl; mi < 2 * hl + 2; ++mi)
        #pragma unroll
        for (int r = 0; r < 4; ++r) s += acc[mi][nj][r];
      s += __shfl_xor(s, 16);
      s += __shfl_xor(s, 32);
      inv[hl][nj] = 1.0f / s;
    }
  // qn = e * inv * rdenom -> qs [tok][ch], packed b64 writes
  #pragma unroll
  for (int mi = 0; mi < 4; ++mi) {
    float4 rd = *(const float4*)(rdenomF + b * 256 + w * 64 + mi * 16 + quad * 4);
    #pragma unroll
    for (int nj = 0; nj < 4; ++nj) {
      u16x4 pk;
      pk[0] = f2b(acc[mi][nj][0] * inv[mi >> 1][nj] * rd.x);
      pk[1] = f2b(acc[mi][nj][1] * inv[mi >> 1][nj] * rd.y);
      pk[2] = f2b(acc[mi][nj][2] * inv[mi >> 1][nj] * rd.z);
      pk[3] = f2b(acc[mi][nj][3] * inv[mi >> 1][nj] * rd.w);
      *(u16x4*)&qs[(nj * 16 + l15) * XTP + w * 64 + mi * 16 + quad * 4] = pk;
    }
  }
  __syncthreads();

  // ---- att GEMM: wave w -> heads 2w,2w+1; D[vch][tok]; K=32 (one step) ----
  f32x4 aacc[2][2][4];
  #pragma unroll
  for (int hl = 0; hl < 2; ++hl)
    #pragma unroll
    for (int mi = 0; mi < 2; ++mi)
      #pragma unroll
      for (int nj = 0; nj < 4; ++nj) aacc[hl][mi][nj] = (f32x4)0.f;
  #pragma unroll
  for (int hl = 0; hl < 2; ++hl) {
    int hh = 2 * w + hl;
    bf16x8 ac[2];
    #pragma unroll
    for (int mi = 0; mi < 2; ++mi)
      ac[mi] = *(const bf16x8*)(ctxT + (((size_t)(b * 8 + hh) * 32 + mi * 16 + l15) << 5) + quad * 8);
    #pragma unroll
    for (int nj = 0; nj < 4; ++nj) {
      bf16x8 bqf = *(const bf16x8*)&qs[(nj * 16 + l15) * XTP + hh * 32 + quad * 8];
      #pragma unroll
      for (int mi = 0; mi < 2; ++mi)
        aacc[hl][mi][nj] = mfma16(ac[mi], bqf, aacc[hl][mi][nj]);
    }
  }
  // write att over qs (each wave writes exactly the columns only it read)
  #pragma unroll
  for (int hl = 0; hl < 2; ++hl)
    #pragma unroll
    for (int mi = 0; mi < 2; ++mi)
      #pragma unroll
      for (int nj = 0; nj < 4; ++nj) {
        u16x4 pk;
        pk[0] = f2b(aacc[hl][mi][nj][0]);
        pk[1] = f2b(aacc[hl][mi][nj][1]);
        pk[2] = f2b(aacc[hl][mi][nj][2]);
        pk[3] = f2b(aacc[hl][mi][nj][3]);
        *(u16x4*)&qs[(nj * 16 + l15) * XTP + (2 * w + hl) * 32 + mi * 16 + quad * 4] = pk;
      }
  __syncthreads();

  // ---- Wr GEMM ----
  #pragma unroll
  for (int mi = 0; mi < 4; ++mi)
    #pragma unroll
    for (int nj = 0; nj < 4; ++nj) acc[mi][nj] = (f32x4)0.f;
  for (int k0 = 0; k0 < NCH; k0 += 32) {
    bf16x8 af[4], bx[4];
    #pragma unroll
    for (int mi = 0; mi < 4; ++mi)
      af[mi] = *(const bf16x8*)(Wrb + (size_t)(w * 64 + mi * 16 + l15) * NCH + k0 + quad * 8);
    #pragma unroll
    for (int nj = 0; nj < 4; ++nj)
      bx[nj] = *(const bf16x8*)&qs[(nj * 16 + l15) * XTP + k0 + quad * 8];
    #pragma unroll
    for (int mi = 0; mi < 4; ++mi)
      #pragma unroll
      for (int nj = 0; nj < 4; ++nj) acc[mi][nj] = mfma16(af[mi], bx[nj], acc[mi][nj]);
  }
  // bias + residual + transposed float4 store
  #pragma unroll
  for (int mi = 0; mi < 4; ++mi) {
    float4 bb = *(const float4*)(br + w * 64 + mi * 16 + quad * 4);
    #pragma unroll
    for (int nj = 0; nj < 4; ++nj) {
      int tok = nj * 16 + l15;
      u16x4 rx = *(const u16x4*)&xs[tok * XTP + w * 64 + mi * 16 + quad * 4];
      float4 o;
      o.x = acc[mi][nj][0] + bb.x + b2f(rx[0]);
      o.y = acc[mi][nj][1] + bb.y + b2f(rx[1]);
      o.z = acc[mi][nj][2] + bb.z + b2f(rx[2]);
      o.w = acc[mi][nj][3] + bb.w + b2f(rx[3]);
      *(float4*)(out + (((size_t)(b * NTOK + g * TT + tok)) << 8) + w * 64 + mi * 16 + quad * 4) = o;
    }
  }
}

extern "C" void kernel_launch(void* const* d_in, const int* in_sizes, int n_in,
                              void* d_out, int out_size, void* d_ws, size_t ws_size,
                              hipStream_t stream) {
  const float* x  = (const float*)d_in[0];
  const float* Wk = (const float*)d_in[1];
  const float* bk = (const float*)d_in[2];
  const float* Wq = (const float*)d_in[3];
  const float* bq = (const float*)d_in[4];
  const float* Wv = (const float*)d_in[5];
  const float* bv = (const float*)d_in[6];
  const float* Wr = (const float*)d_in[7];
  const float* br = (const float*)d_in[8];
  float* out = (float*)d_out;

  // ws layout (26.3 MB total)
  char* wsb = (char*)d_ws;
  u16*   ctxPart   = (u16*)wsb;                         // 512*8192 u16  = 8 MB
  float* denomPart = (float*)(wsb + 8388608);           // 512*256 f32   = 0.5 MB
  u16*   ctxT      = (u16*)(wsb + 8912896);             // 32768 u16     = 64 KB
  float* rdenomF   = (float*)(wsb + 8978432);           // 1024 f32      = 4 KB
  u16*   wbf       = (u16*)(wsb + 8982528);             // 4*65536 u16   = 0.5 MB
  u16*   xT        = (u16*)(wsb + 9506816);             // 4*8192*256 u16= 16 MB

  hipLaunchKernelGGL(k_prep, dim3(2112), dim3(256), 0, stream,
                     x, Wk, Wq, Wv, Wr, xT, wbf);
  hipLaunchKernelGGL(k_ctx, dim3(512), dim3(256), 0, stream,
                     xT, wbf, bk, bv, ctxPart, denomPart);
  hipLaunchKernelGGL(k_red, dim3(132), dim3(256), 0, stream,
                     ctxPart, denomPart, ctxT, rdenomF);
  hipLaunchKernelGGL(k_out, dim3(512), dim3(256), 0, stream,
                     xT, wbf, bq, br, ctxT, rdenomF, out);
}

// Round 3
// 148.498 us; speedup vs baseline: 3.0881x; 1.0693x over previous
//
#include <hip/hip_runtime.h>

#define NTOK 8192
#define NCH  256
#define TT   64          // tokens per tile
#define XTP  264         // stride (u16) for [tok][ch] LDS tiles (16B-aligned rows)
#define EKP  72          // stride (u16) for [ch][tok] LDS tiles (16B-aligned rows)

typedef unsigned short u16;
typedef __attribute__((ext_vector_type(8))) short bf16x8;   // MFMA A/B frag (4 VGPR)
typedef __attribute__((ext_vector_type(4))) float f32x4;    // MFMA C/D frag
typedef __attribute__((ext_vector_type(8))) unsigned short u16x8;
typedef __attribute__((ext_vector_type(4))) unsigned short u16x4;

__device__ __forceinline__ float b2f(u16 h){
  union{unsigned u; float f;} x; x.u = ((unsigned)h) << 16; return x.f;
}
__device__ __forceinline__ u16 f2b(float f){
  union{float f; unsigned u;} x; x.f = f;
  unsigned u = x.u;
  return (u16)((u + 0x7FFFu + ((u >> 16) & 1u)) >> 16);   // RNE
}
__device__ __forceinline__ f32x4 mfma16(bf16x8 a, bf16x8 b, f32x4 c){
  return __builtin_amdgcn_mfma_f32_16x16x32_bf16(a, b, c, 0, 0, 0);
}

// ---------------------------------------------------------------------------
// k_prep: (a) transpose+convert x fp32 [b][ch][tok] -> xT bf16 [b][tok][ch]
//         (b) convert Wk/Wq/Wv/Wr fp32 -> bf16 row-major into wbf
// ---------------------------------------------------------------------------
__global__ __launch_bounds__(256)
void k_prep(const float* __restrict__ x,
            const float* __restrict__ Wk, const float* __restrict__ Wq,
            const float* __restrict__ Wv, const float* __restrict__ Wr,
            u16* __restrict__ xT, u16* __restrict__ wbf)
{
  __shared__ u16 ts[64 * 68];
  const int t = threadIdx.x, bid = blockIdx.x;
  if (bid < 2048) {
    const int b = bid >> 9, rem = bid & 511, tg = rem >> 2, cg = rem & 3;
    const float* xb = x + (size_t)b * NCH * NTOK;
    #pragma unroll
    for (int p = 0; p < 4; ++p) {
      int cl = p * 16 + (t >> 4);
      int tl = (t & 15) * 4;
      float4 v = *(const float4*)(xb + (size_t)(cg * 64 + cl) * NTOK + tg * 64 + tl);
      u16x4 pk; pk[0]=f2b(v.x); pk[1]=f2b(v.y); pk[2]=f2b(v.z); pk[3]=f2b(v.w);
      *(u16x4*)&ts[cl * 68 + tl] = pk;
    }
    __syncthreads();
    #pragma unroll
    for (int p = 0; p < 2; ++p) {
      int tl = p * 32 + (t >> 3);
      int cl = (t & 7) * 8;
      u16x8 o;
      #pragma unroll
      for (int j = 0; j < 8; ++j) o[j] = ts[(cl + j) * 68 + tl];
      *(u16x8*)(xT + (((size_t)(b * NTOK + tg * 64 + tl)) << 8) + cg * 64 + cl) = o;
    }
  } else {
    const int wb = bid - 2048;           // 64 blocks, 16 per matrix
    const int mat = wb >> 4;
    const float* src = (mat == 0) ? Wk : (mat == 1) ? Wq : (mat == 2) ? Wv : Wr;
    u16* dst = wbf + mat * 65536;
    const int base = (wb & 15) * 4096 + t * 16;
    #pragma unroll
    for (int i = 0; i < 4; ++i) {
      float4 v = *(const float4*)(src + base + i * 4);
      u16x4 pk; pk[0]=f2b(v.x); pk[1]=f2b(v.y); pk[2]=f2b(v.z); pk[3]=f2b(v.w);
      *(u16x4*)(dst + base + i * 4) = pk;
    }
  }
}

// ---------------------------------------------------------------------------
// k_ctx: 512 threads, 8 waves; wave w owns out-ch slab [32w, 32w+32) == head w.
// K-GEMM(MFMA)->exp->ekb LDS; V-GEMM->vt (aliased over x tile); ctx GEMM per
// head + denom row-sums -> partials.
// ---------------------------------------------------------------------------
__global__ __launch_bounds__(512)
void k_ctx(const u16* __restrict__ xT, const u16* __restrict__ wbf,
           const float* __restrict__ bk, const float* __restrict__ bv,
           u16* __restrict__ ctxPart, float* __restrict__ denomPart)
{
  __shared__ u16 bufA[NCH * EKP];   // phase 1: xT tile [64][XTP]; phase 2: vt [256][EKP]
  __shared__ u16 ekb[NCH * EKP];    // exp(K) [ch][tok]

  const int t = threadIdx.x;
  const int b = blockIdx.x >> 7, g = blockIdx.x & 127;
  const int w = t >> 6, lane = t & 63;
  const int l15 = lane & 15, quad = lane >> 4;
  const u16* Wkb = wbf;
  const u16* Wvb = wbf + 2 * 65536;

  // ---- stage xT tile (32 KB contiguous, coalesced 16B) ----
  {
    const u16* src = xT + ((size_t)(b * NTOK + g * TT) << 8);
    #pragma unroll
    for (int i = 0; i < 4; ++i) {
      int f = i * 4096 + t * 8;
      int tok = f >> 8, ch = f & 255;
      *(u16x8*)&bufA[tok * XTP + ch] = *(const u16x8*)(src + f);
    }
  }
  __syncthreads();

  f32x4 acc[2][4];

  // ---- K GEMM: D[och][tok], wave w owns och [32w, 32w+32) ----
  #pragma unroll
  for (int mi = 0; mi < 2; ++mi)
    #pragma unroll
    for (int nj = 0; nj < 4; ++nj) acc[mi][nj] = (f32x4)0.f;
  for (int k0 = 0; k0 < NCH; k0 += 32) {
    bf16x8 af[2], bx[4];
    #pragma unroll
    for (int mi = 0; mi < 2; ++mi)
      af[mi] = *(const bf16x8*)(Wkb + (size_t)(w * 32 + mi * 16 + l15) * NCH + k0 + quad * 8);
    #pragma unroll
    for (int nj = 0; nj < 4; ++nj)
      bx[nj] = *(const bf16x8*)&bufA[(nj * 16 + l15) * XTP + k0 + quad * 8];
    #pragma unroll
    for (int mi = 0; mi < 2; ++mi)
      #pragma unroll
      for (int nj = 0; nj < 4; ++nj) acc[mi][nj] = mfma16(af[mi], bx[nj], acc[mi][nj]);
  }
  // epilogue: bias + exp -> ekb [ch][tok]
  #pragma unroll
  for (int mi = 0; mi < 2; ++mi) {
    float4 bb = *(const float4*)(bk + w * 32 + mi * 16 + quad * 4);
    #pragma unroll
    for (int nj = 0; nj < 4; ++nj) {
      int tok = nj * 16 + l15, chb = w * 32 + mi * 16 + quad * 4;
      ekb[(chb + 0) * EKP + tok] = f2b(__expf(acc[mi][nj][0] + bb.x));
      ekb[(chb + 1) * EKP + tok] = f2b(__expf(acc[mi][nj][1] + bb.y));
      ekb[(chb + 2) * EKP + tok] = f2b(__expf(acc[mi][nj][2] + bb.z));
      ekb[(chb + 3) * EKP + tok] = f2b(__expf(acc[mi][nj][3] + bb.w));
    }
  }

  // ---- V GEMM (re-uses acc regs) ----
  #pragma unroll
  for (int mi = 0; mi < 2; ++mi)
    #pragma unroll
    for (int nj = 0; nj < 4; ++nj) acc[mi][nj] = (f32x4)0.f;
  for (int k0 = 0; k0 < NCH; k0 += 32) {
    bf16x8 af[2], bx[4];
    #pragma unroll
    for (int mi = 0; mi < 2; ++mi)
      af[mi] = *(const bf16x8*)(Wvb + (size_t)(w * 32 + mi * 16 + l15) * NCH + k0 + quad * 8);
    #pragma unroll
    for (int nj = 0; nj < 4; ++nj)
      bx[nj] = *(const bf16x8*)&bufA[(nj * 16 + l15) * XTP + k0 + quad * 8];
    #pragma unroll
    for (int mi = 0; mi < 2; ++mi)
      #pragma unroll
      for (int nj = 0; nj < 4; ++nj) acc[mi][nj] = mfma16(af[mi], bx[nj], acc[mi][nj]);
  }
  __syncthreads();   // all waves done reading x tile; safe to overwrite with vt
  #pragma unroll
  for (int mi = 0; mi < 2; ++mi) {
    float4 bb = *(const float4*)(bv + w * 32 + mi * 16 + quad * 4);
    #pragma unroll
    for (int nj = 0; nj < 4; ++nj) {
      int tok = nj * 16 + l15, chb = w * 32 + mi * 16 + quad * 4;
      bufA[(chb + 0) * EKP + tok] = f2b(acc[mi][nj][0] + bb.x);
      bufA[(chb + 1) * EKP + tok] = f2b(acc[mi][nj][1] + bb.y);
      bufA[(chb + 2) * EKP + tok] = f2b(acc[mi][nj][2] + bb.z);
      bufA[(chb + 3) * EKP + tok] = f2b(acc[mi][nj][3] + bb.w);
    }
  }
  __syncthreads();

  // ---- ctx GEMM: wave w -> head w. D[kk][vch] = sum_s ek*v ----
  f32x4 cacc[2][2];
  #pragma unroll
  for (int mi = 0; mi < 2; ++mi)
    #pragma unroll
    for (int nj = 0; nj < 2; ++nj) cacc[mi][nj] = (f32x4)0.f;
  #pragma unroll
  for (int kc = 0; kc < 2; ++kc) {
    bf16x8 ae[2], bvv[2];
    #pragma unroll
    for (int mi = 0; mi < 2; ++mi)
      ae[mi] = *(const bf16x8*)&ekb[(w * 32 + mi * 16 + l15) * EKP + kc * 32 + quad * 8];
    #pragma unroll
    for (int nj = 0; nj < 2; ++nj)
      bvv[nj] = *(const bf16x8*)&bufA[(w * 32 + nj * 16 + l15) * EKP + kc * 32 + quad * 8];
    #pragma unroll
    for (int mi = 0; mi < 2; ++mi)
      #pragma unroll
      for (int nj = 0; nj < 2; ++nj)
        cacc[mi][nj] = mfma16(ae[mi], bvv[nj], cacc[mi][nj]);
  }
  // denominator: threads 0..255 each sum one ek row over 64 tokens
  float dsum = 0.f;
  if (t < 256) {
    #pragma unroll
    for (int s = 0; s < TT; s += 8) {
      u16x8 v = *(const u16x8*)&ekb[t * EKP + s];
      #pragma unroll
      for (int j = 0; j < 8; ++j) dsum += b2f(v[j]);
    }
  }

  // ---- store partials (bf16 ctx + fp32 denom) ----
  u16* cp = ctxPart + ((size_t)(b * 128 + g) << 13);
  #pragma unroll
  for (int mi = 0; mi < 2; ++mi)
    #pragma unroll
    for (int nj = 0; nj < 2; ++nj)
      #pragma unroll
      for (int r = 0; r < 4; ++r) {
        int e = ((w * 32 + mi * 16 + quad * 4 + r) << 5) + nj * 16 + l15;
        cp[e] = f2b(cacc[mi][nj][r]);
      }
  if (t < 256)
    denomPart[(size_t)(b * 128 + g) * 256 + t] = dsum;
}

// ---------------------------------------------------------------------------
// k_red: sum 128 partials -> ctxT bf16 [b][h][vch][kk] (A-operand-ready) and
// rdenomF = 1/denom fp32 [b][256]
// ---------------------------------------------------------------------------
__global__ __launch_bounds__(256)
void k_red(const u16* __restrict__ ctxPart, const float* __restrict__ denomPart,
           u16* __restrict__ ctxT, float* __restrict__ rdenomF)
{
  int i = blockIdx.x * 256 + threadIdx.x;
  if (i < 32768) {
    int b = i >> 13, e = i & 8191;
    const u16* p = ctxPart + ((size_t)(b * 128) << 13) + e;
    float s = 0.f;
    for (int g = 0; g < 128; ++g) s += b2f(p[(size_t)g << 13]);
    int hh = e >> 10, kk = (e >> 5) & 31, vch = e & 31;
    ctxT[(((b * 8 + hh) * 32 + vch) << 5) + kk] = f2b(s);
  } else if (i < 33792) {
    int j = i - 32768, b = j >> 8, ch = j & 255;
    const float* p = denomPart + (size_t)(b * 128) * 256 + ch;
    float s = 0.f;
    for (int g = 0; g < 128; ++g) s += p[(size_t)g << 8];
    rdenomF[j] = 1.0f / s;
  }
}

// ---------------------------------------------------------------------------
// k_out: 512 threads, 8 waves; wave w owns head w / out-ch slab [32w,32w+32).
// Q-GEMM(MFMA)->exp->head softmax (shfl over quads) * rdenom -> qn LDS
// [tok][ch]; att GEMM (A=ctxT global, B=qn, out aliased over qn, wave-
// exclusive cols); Wr-GEMM; +bias +bf16 residual; coalesced float4 store.
// ---------------------------------------------------------------------------
__global__ __launch_bounds__(512)
void k_out(const u16* __restrict__ xT, const u16* __restrict__ wbf,
           const float* __restrict__ bq, const float* __restrict__ br,
           const u16* __restrict__ ctxT, const float* __restrict__ rdenomF,
           float* __restrict__ out)
{
  __shared__ u16 xs[TT * XTP];
  __shared__ u16 qs[TT * XTP];   // qn, then aliased by att (wave-exclusive cols)

  const int t = threadIdx.x;
  const int b = blockIdx.x >> 7, g = blockIdx.x & 127;
  const int w = t >> 6, lane = t & 63;
  const int l15 = lane & 15, quad = lane >> 4;
  const u16* Wqb = wbf + 65536;
  const u16* Wrb = wbf + 3 * 65536;

  {
    const u16* src = xT + ((size_t)(b * NTOK + g * TT) << 8);
    #pragma unroll
    for (int i = 0; i < 4; ++i) {
      int f = i * 4096 + t * 8;
      int tok = f >> 8, ch = f & 255;
      *(u16x8*)&xs[tok * XTP + ch] = *(const u16x8*)(src + f);
    }
  }
  __syncthreads();

  f32x4 acc[2][4];
  // ---- Q GEMM: wave w -> och [32w, 32w+32) == head w ----
  #pragma unroll
  for (int mi = 0; mi < 2; ++mi)
    #pragma unroll
    for (int nj = 0; nj < 4; ++nj) acc[mi][nj] = (f32x4)0.f;
  for (int k0 = 0; k0 < NCH; k0 += 32) {
    bf16x8 af[2], bx[4];
    #pragma unroll
    for (int mi = 0; mi < 2; ++mi)
      af[mi] = *(const bf16x8*)(Wqb + (size_t)(w * 32 + mi * 16 + l15) * NCH + k0 + quad * 8);
    #pragma unroll
    for (int nj = 0; nj < 4; ++nj)
      bx[nj] = *(const bf16x8*)&xs[(nj * 16 + l15) * XTP + k0 + quad * 8];
    #pragma unroll
    for (int mi = 0; mi < 2; ++mi)
      #pragma unroll
      for (int nj = 0; nj < 4; ++nj) acc[mi][nj] = mfma16(af[mi], bx[nj], acc[mi][nj]);
  }
  // bias + exp (in place)
  #pragma unroll
  for (int mi = 0; mi < 2; ++mi) {
    float4 bb = *(const float4*)(bq + w * 32 + mi * 16 + quad * 4);
    #pragma unroll
    for (int nj = 0; nj < 4; ++nj) {
      acc[mi][nj][0] = __expf(acc[mi][nj][0] + bb.x);
      acc[mi][nj][1] = __expf(acc[mi][nj][1] + bb.y);
      acc[mi][nj][2] = __expf(acc[mi][nj][2] + bb.z);
      acc[mi][nj][3] = __expf(acc[mi][nj][3] + bb.w);
    }
  }
  // per-(head, token) softmax denom: sum over mi,r in-lane + quad reduction
  float inv[4];
  #pragma unroll
  for (int nj = 0; nj < 4; ++nj) {
    float s = 0.f;
    #pragma unroll
    for (int mi = 0; mi < 2; ++mi)
      #pragma unroll
      for (int r = 0; r < 4; ++r) s += acc[mi][nj][r];
    s += __shfl_xor(s, 16);
    s += __shfl_xor(s, 32);
    inv[nj] = 1.0f / s;
  }
  // qn = e * inv * rdenom -> qs [tok][ch], packed b64 writes
  #pragma unroll
  for (int mi = 0; mi < 2; ++mi) {
    float4 rd = *(const float4*)(rdenomF + b * 256 + w * 32 + mi * 16 + quad * 4);
    #pragma unroll
    for (int nj = 0; nj < 4; ++nj) {
      u16x4 pk;
      pk[0] = f2b(acc[mi][nj][0] * inv[nj] * rd.x);
      pk[1] = f2b(acc[mi][nj][1] * inv[nj] * rd.y);
      pk[2] = f2b(acc[mi][nj][2] * inv[nj] * rd.z);
      pk[3] = f2b(acc[mi][nj][3] * inv[nj] * rd.w);
      *(u16x4*)&qs[(nj * 16 + l15) * XTP + w * 32 + mi * 16 + quad * 4] = pk;
    }
  }
  __syncthreads();

  // ---- att GEMM: wave w -> head w; D[vch][tok]; K=32 (one step) ----
  f32x4 aacc[2][4];
  {
    bf16x8 ac[2];
    #pragma unroll
    for (int mi = 0; mi < 2; ++mi)
      ac[mi] = *(const bf16x8*)(ctxT + (((size_t)(b * 8 + w) * 32 + mi * 16 + l15) << 5) + quad * 8);
    #pragma unroll
    for (int nj = 0; nj < 4; ++nj) {
      bf16x8 bqf = *(const bf16x8*)&qs[(nj * 16 + l15) * XTP + w * 32 + quad * 8];
      #pragma unroll
      for (int mi = 0; mi < 2; ++mi)
        aacc[mi][nj] = mfma16(ac[mi], bqf, (f32x4)0.f);
    }
  }
  // write att over qs (each wave writes exactly the columns only it read)
  #pragma unroll
  for (int mi = 0; mi < 2; ++mi)
    #pragma unroll
    for (int nj = 0; nj < 4; ++nj) {
      u16x4 pk;
      pk[0] = f2b(aacc[mi][nj][0]);
      pk[1] = f2b(aacc[mi][nj][1]);
      pk[2] = f2b(aacc[mi][nj][2]);
      pk[3] = f2b(aacc[mi][nj][3]);
      *(u16x4*)&qs[(nj * 16 + l15) * XTP + w * 32 + mi * 16 + quad * 4] = pk;
    }
  __syncthreads();

  // ---- Wr GEMM ----
  #pragma unroll
  for (int mi = 0; mi < 2; ++mi)
    #pragma unroll
    for (int nj = 0; nj < 4; ++nj) acc[mi][nj] = (f32x4)0.f;
  for (int k0 = 0; k0 < NCH; k0 += 32) {
    bf16x8 af[2], bx[4];
    #pragma unroll
    for (int mi = 0; mi < 2; ++mi)
      af[mi] = *(const bf16x8*)(Wrb + (size_t)(w * 32 + mi * 16 + l15) * NCH + k0 + quad * 8);
    #pragma unroll
    for (int nj = 0; nj < 4; ++nj)
      bx[nj] = *(const bf16x8*)&qs[(nj * 16 + l15) * XTP + k0 + quad * 8];
    #pragma unroll
    for (int mi = 0; mi < 2; ++mi)
      #pragma unroll
      for (int nj = 0; nj < 4; ++nj) acc[mi][nj] = mfma16(af[mi], bx[nj], acc[mi][nj]);
  }
  // bias + residual + transposed float4 store
  #pragma unroll
  for (int mi = 0; mi < 2; ++mi) {
    float4 bb = *(const float4*)(br + w * 32 + mi * 16 + quad * 4);
    #pragma unroll
    for (int nj = 0; nj < 4; ++nj) {
      int tok = nj * 16 + l15;
      u16x4 rx = *(const u16x4*)&xs[tok * XTP + w * 32 + mi * 16 + quad * 4];
      float4 o;
      o.x = acc[mi][nj][0] + bb.x + b2f(rx[0]);
      o.y = acc[mi][nj][1] + bb.y + b2f(rx[1]);
      o.z = acc[mi][nj][2] + bb.z + b2f(rx[2]);
      o.w = acc[mi][nj][3] + bb.w + b2f(rx[3]);
      *(float4*)(out + (((size_t)(b * NTOK + g * TT + tok)) << 8) + w * 32 + mi * 16 + quad * 4) = o;
    }
  }
}

extern "C" void kernel_launch(void* const* d_in, const int* in_sizes, int n_in,
                              void* d_out, int out_size, void* d_ws, size_t ws_size,
                              hipStream_t stream) {
  const float* x  = (const float*)d_in[0];
  const float* Wk = (const float*)d_in[1];
  const float* bk = (const float*)d_in[2];
  const float* Wq = (const float*)d_in[3];
  const float* bq = (const float*)d_in[4];
  const float* Wv = (const float*)d_in[5];
  const float* bv = (const float*)d_in[6];
  const float* Wr = (const float*)d_in[7];
  const float* br = (const float*)d_in[8];
  float* out = (float*)d_out;

  // ws layout (26.3 MB total)
  char* wsb = (char*)d_ws;
  u16*   ctxPart   = (u16*)wsb;                         // 512*8192 u16  = 8 MB
  float* denomPart = (float*)(wsb + 8388608);           // 512*256 f32   = 0.5 MB
  u16*   ctxT      = (u16*)(wsb + 8912896);             // 32768 u16     = 64 KB
  float* rdenomF   = (float*)(wsb + 8978432);           // 1024 f32      = 4 KB
  u16*   wbf       = (u16*)(wsb + 8982528);             // 4*65536 u16   = 0.5 MB
  u16*   xT        = (u16*)(wsb + 9506816);             // 4*8192*256 u16= 16 MB

  hipLaunchKernelGGL(k_prep, dim3(2112), dim3(256), 0, stream,
                     x, Wk, Wq, Wv, Wr, xT, wbf);
  hipLaunchKernelGGL(k_ctx, dim3(512), dim3(512), 0, stream,
                     xT, wbf, bk, bv, ctxPart, denomPart);
  hipLaunchKernelGGL(k_red, dim3(132), dim3(256), 0, stream,
                     ctxPart, denomPart, ctxT, rdenomF);
  hipLaunchKernelGGL(k_out, dim3(512), dim3(512), 0, stream,
                     xT, wbf, bq, br, ctxT, rdenomF, out);
}